// Round 1
// baseline (241.471 us; speedup 1.0000x reference)
//
#include <hip/hip_runtime.h>
#include <hip/hip_bf16.h>

typedef unsigned short u16;
typedef __attribute__((ext_vector_type(8))) short bf16x8;
typedef __attribute__((ext_vector_type(4))) float f32x4;

#define LOG2E 1.44269504088896f

__device__ __forceinline__ u16 f2bf(float f) {
  unsigned u = __float_as_uint(f);
  u += 0x7FFFu + ((u >> 16) & 1u);   // round-to-nearest-even
  return (u16)(u >> 16);
}
__device__ __forceinline__ float bf2f(u16 v) {
  return __uint_as_float(((unsigned)v) << 16);
}

// ---------------------------------------------------------------------------
// Phase 1: per-head QKV projection.
//   q_ws: [B][H][S][64] bf16, plain row-major, pre-scaled by 0.125
//   k_ws: [B][H][16 kv-blocks] of 8KB images: byte = row*128 + ((col*2)^((row&7)<<4))
//   vt_ws: same image format but row = e (output dim), col = token-in-block
// ---------------------------------------------------------------------------
__global__ __launch_bounds__(256) void qkv_proj_kernel(
    const float* __restrict__ x,
    const float* __restrict__ Wq, const float* __restrict__ bq,
    const float* __restrict__ Wk, const float* __restrict__ bk,
    const float* __restrict__ Wv, const float* __restrict__ bv,
    u16* __restrict__ qws, u16* __restrict__ kws, u16* __restrict__ vtws)
{
  constexpr int S = 1024, D = 1024, H = 16;
  const int tid  = threadIdx.x;
  const int lane = tid & 63;
  const int w    = tid >> 6;
  const int st   = blockIdx.x;   // s-tile (128 tokens)
  const int h    = blockIdx.y;
  const int b    = blockIdx.z;
  const int s0   = st * 128;
  const int col  = lane & 15;
  const int lhi  = lane >> 4;

  __shared__ u16 xs[128 * 72];      // x tile bf16, stride 72 (2-way bank = free)
  __shared__ u16 wsm[3 * 64 * 72];  // Wq/Wk/Wv for head h
  __shared__ u16 ost[4 * 2304];     // per-wave output staging

  // ---- stage x tile and weights (fp32 -> bf16) ----
  {
    const int r = tid >> 4;          // 0..15
    const int c = (tid & 15) * 4;    // 0..60
#pragma unroll
    for (int p = 0; p < 8; ++p) {
      const int row = p * 16 + r;
      const float4 v = *(const float4*)(x + ((size_t)b * S + s0 + row) * D + h * 64 + c);
      ushort4 u; u.x = f2bf(v.x); u.y = f2bf(v.y); u.z = f2bf(v.z); u.w = f2bf(v.w);
      *(ushort4*)(&xs[row * 72 + c]) = u;
    }
    const float* Wp[3] = {Wq, Wk, Wv};
#pragma unroll
    for (int o = 0; o < 3; ++o) {
      const float* Wh = Wp[o] + (size_t)h * 4096;
#pragma unroll
      for (int p = 0; p < 4; ++p) {
        const int row = p * 16 + r;
        const float4 v = *(const float4*)(Wh + row * 64 + c);
        ushort4 u; u.x = f2bf(v.x); u.y = f2bf(v.y); u.z = f2bf(v.z); u.w = f2bf(v.w);
        *(ushort4*)(&wsm[o * 4608 + row * 72 + c]) = u;
      }
    }
  }
  __syncthreads();

  // A-fragments: wave w owns tokens [w*32, w*32+32)
  bf16x8 af[2][2];
#pragma unroll
  for (int qt = 0; qt < 2; ++qt)
#pragma unroll
    for (int ks = 0; ks < 2; ++ks)
      af[qt][ks] = *(const bf16x8*)(&xs[(w * 32 + qt * 16 + col) * 72 + ks * 32 + lhi * 8]);

  u16* ow = &ost[w * 2304];

#pragma unroll
  for (int o = 0; o < 3; ++o) {
    f32x4 acc[2][4];
#pragma unroll
    for (int qt = 0; qt < 2; ++qt)
#pragma unroll
      for (int et = 0; et < 4; ++et) acc[qt][et] = f32x4{0.f, 0.f, 0.f, 0.f};

#pragma unroll
    for (int et = 0; et < 4; ++et)
#pragma unroll
      for (int ks = 0; ks < 2; ++ks) {
        const bf16x8 bfr = *(const bf16x8*)(&wsm[o * 4608 + (et * 16 + col) * 72 + ks * 32 + lhi * 8]);
        acc[0][et] = __builtin_amdgcn_mfma_f32_16x16x32_bf16(af[0][ks], bfr, acc[0][et], 0, 0, 0);
        acc[1][et] = __builtin_amdgcn_mfma_f32_16x16x32_bf16(af[1][ks], bfr, acc[1][et], 0, 0, 0);
      }

    const float* bp = (o == 0) ? bq : (o == 1) ? bk : bv;
    float bias[4];
#pragma unroll
    for (int et = 0; et < 4; ++et) bias[et] = bp[h * 64 + et * 16 + col];
    const float mul = (o == 0) ? 0.125f : 1.0f;   // fold 1/sqrt(HD) into Q

    if (o < 2) {
      // stage as [32 t][72 e]
#pragma unroll
      for (int qt = 0; qt < 2; ++qt)
#pragma unroll
        for (int et = 0; et < 4; ++et)
#pragma unroll
          for (int j = 0; j < 4; ++j)
            ow[(qt * 16 + lhi * 4 + j) * 72 + et * 16 + col] =
                f2bf((acc[qt][et][j] + bias[et]) * mul);
      asm volatile("s_waitcnt lgkmcnt(0)" ::: "memory");  // cross-lane RAW in wave
#pragma unroll
      for (int p = 0; p < 8; ++p) {
        const int rl = p * 4 + lhi;                         // 0..31
        const ushort4 dta = *(const ushort4*)(&ow[rl * 72 + col * 4]);
        if (o == 0) {
          const size_t off = (((size_t)b * H + h) * S + s0 + w * 32 + rl) * 64 + col * 4;
          *(ushort4*)(qws + off) = dta;
        } else {
          const int tg  = s0 + w * 32 + rl;
          const int kb  = tg >> 6, rim = tg & 63;
          const int byt = (col * 8) ^ ((rim & 7) << 4);     // pre-swizzle
          const size_t off = (((size_t)b * H + h) * 16 + kb) * 4096 + rim * 64 + (byt >> 1);
          *(ushort4*)(kws + off) = dta;
        }
      }
    } else {
      // V: stage transposed as [64 e][36 t] (j-regs are consecutive tokens -> 8B packs)
#pragma unroll
      for (int qt = 0; qt < 2; ++qt)
#pragma unroll
        for (int et = 0; et < 4; ++et) {
          ushort4 u;
          u.x = f2bf(acc[qt][et][0] + bias[et]);
          u.y = f2bf(acc[qt][et][1] + bias[et]);
          u.z = f2bf(acc[qt][et][2] + bias[et]);
          u.w = f2bf(acc[qt][et][3] + bias[et]);
          *(ushort4*)(&ow[(et * 16 + col) * 36 + qt * 16 + lhi * 4]) = u;
        }
      asm volatile("s_waitcnt lgkmcnt(0)" ::: "memory");
#pragma unroll
      for (int p = 0; p < 8; ++p) {
        const int e = p * 8 + (lane >> 3);   // 0..63
        const int c = lane & 7;              // token chunk
        const ushort4 dta = *(const ushort4*)(&ow[e * 36 + c * 4]);
        const int tl  = w * 32 + c * 4;                      // token within 128-tile
        const int kb  = (s0 + tl) >> 6;
        const int kc  = (s0 + tl) & 63;
        const int byt = (kc * 2) ^ ((e & 7) << 4);
        const size_t off = (((size_t)b * H + h) * 16 + kb) * 4096 + e * 64 + (byt >> 1);
        *(ushort4*)(vtws + off) = dta;
      }
    }
    __syncthreads();   // WAR on ost reuse across o
  }
}

// ---------------------------------------------------------------------------
// Phase 2: flash attention. 4 waves x 32 q-rows (QT=128), KV-block 64,
// double-buffered global_load_lds staging of pre-swizzled K / V^T images.
// ---------------------------------------------------------------------------
__global__ __launch_bounds__(256) void attn_kernel(
    const u16* __restrict__ qws, const u16* __restrict__ kws,
    const u16* __restrict__ vtws, float* __restrict__ out)
{
  constexpr int S = 1024, D = 1024, H = 16;
  const int tid  = threadIdx.x;
  const int lane = tid & 63;
  const int w    = tid >> 6;
  const int qb   = blockIdx.x;
  const int h    = blockIdx.y;
  const int b    = blockIdx.z;
  const int col  = lane & 15;
  const int lhi  = lane >> 4;

  __shared__ u16 kbuf[2 * 4096];   // 2 x 8KB swizzled K images
  __shared__ u16 vbuf[2 * 4096];   // 2 x 8KB swizzled V^T images
  __shared__ u16 pst[4 * 2304];    // per-wave P staging [32][72]

  const size_t bh = (size_t)b * H + h;
  const u16* qbase = qws + (bh * S + qb * 128 + w * 32) * 64;
  const u16* kimg0 = kws + bh * 16 * 4096;
  const u16* vimg0 = vtws + bh * 16 * 4096;

  // Q fragments live in registers for the whole KV loop (pre-scaled by 0.125)
  bf16x8 af[2][2];
#pragma unroll
  for (int qt = 0; qt < 2; ++qt)
#pragma unroll
    for (int ks = 0; ks < 2; ++ks)
      af[qt][ks] = *(const bf16x8*)(qbase + (qt * 16 + col) * 64 + ks * 32 + lhi * 8);

  f32x4 oacc[2][4];
  float mrow[2][4], lrow[2][4];
#pragma unroll
  for (int qt = 0; qt < 2; ++qt) {
#pragma unroll
    for (int et = 0; et < 4; ++et) oacc[qt][et] = f32x4{0.f, 0.f, 0.f, 0.f};
#pragma unroll
    for (int j = 0; j < 4; ++j) { mrow[qt][j] = -1e30f; lrow[qt][j] = 0.f; }
  }

  auto stage = [&](int buf, int kb) {
    const u16* kimg = kimg0 + kb * 4096;
    const u16* vimg = vimg0 + kb * 4096;
#pragma unroll
    for (int i = 0; i < 2; ++i) {
      const int chunk = w + i * 4;   // wave-uniform
      __builtin_amdgcn_global_load_lds(
          (const __attribute__((address_space(1))) unsigned int*)(kimg + chunk * 512 + lane * 8),
          (__attribute__((address_space(3))) unsigned int*)(&kbuf[buf * 4096 + chunk * 512]),
          16, 0, 0);
      __builtin_amdgcn_global_load_lds(
          (const __attribute__((address_space(1))) unsigned int*)(vimg + chunk * 512 + lane * 8),
          (__attribute__((address_space(3))) unsigned int*)(&vbuf[buf * 4096 + chunk * 512]),
          16, 0, 0);
    }
  };

  u16* pw = &pst[w * 2304];

  stage(0, 0);
  __syncthreads();

  int cur = 0;
  for (int kb = 0; kb < 16; ++kb) {
    if (kb < 15) stage(cur ^ 1, kb + 1);

    // ---- S = Q K^T ----
    const u16* kp = &kbuf[cur * 4096];
    f32x4 sa[2][4];
#pragma unroll
    for (int qt = 0; qt < 2; ++qt)
#pragma unroll
      for (int kt = 0; kt < 4; ++kt) sa[qt][kt] = f32x4{0.f, 0.f, 0.f, 0.f};

#pragma unroll
    for (int ks = 0; ks < 2; ++ks)
#pragma unroll
      for (int kt = 0; kt < 4; ++kt) {
        const int kk  = kt * 16 + col;
        const int byt = (ks * 64 + lhi * 16) ^ ((kk & 7) << 4);
        const bf16x8 bk_ = *(const bf16x8*)(kp + kk * 64 + (byt >> 1));
        sa[0][kt] = __builtin_amdgcn_mfma_f32_16x16x32_bf16(af[0][ks], bk_, sa[0][kt], 0, 0, 0);
        sa[1][kt] = __builtin_amdgcn_mfma_f32_16x16x32_bf16(af[1][ks], bk_, sa[1][kt], 0, 0, 0);
      }

    // ---- online softmax (wave-parallel, 16-lane groups own 4 q-rows) ----
#pragma unroll
    for (int qt = 0; qt < 2; ++qt)
#pragma unroll
      for (int j = 0; j < 4; ++j) {
        float mx = fmaxf(fmaxf(sa[qt][0][j], sa[qt][1][j]),
                         fmaxf(sa[qt][2][j], sa[qt][3][j]));
        mx = fmaxf(mx, __shfl_xor(mx, 1));
        mx = fmaxf(mx, __shfl_xor(mx, 2));
        mx = fmaxf(mx, __shfl_xor(mx, 4));
        mx = fmaxf(mx, __shfl_xor(mx, 8));
        const float mnew  = fmaxf(mrow[qt][j], mx);
        const float alpha = exp2f((mrow[qt][j] - mnew) * LOG2E);
        mrow[qt][j] = mnew;
        float rs = 0.f;
#pragma unroll
        for (int kt = 0; kt < 4; ++kt) {
          const float p = exp2f((sa[qt][kt][j] - mnew) * LOG2E);
          const u16 pb = f2bf(p);
          rs += bf2f(pb);   // normalizer matches bf16 numerator
          pw[(qt * 16 + lhi * 4 + j) * 72 + kt * 16 + col] = pb;
        }
        rs += __shfl_xor(rs, 1);
        rs += __shfl_xor(rs, 2);
        rs += __shfl_xor(rs, 4);
        rs += __shfl_xor(rs, 8);
        lrow[qt][j] = lrow[qt][j] * alpha + rs;
#pragma unroll
        for (int et = 0; et < 4; ++et) oacc[qt][et][j] *= alpha;
      }

    asm volatile("s_waitcnt lgkmcnt(0)" ::: "memory");  // P cross-lane RAW

    bf16x8 pa[2][2];
#pragma unroll
    for (int qt = 0; qt < 2; ++qt)
#pragma unroll
      for (int ks = 0; ks < 2; ++ks)
        pa[qt][ks] = *(const bf16x8*)(pw + (qt * 16 + col) * 72 + ks * 32 + lhi * 8);

    // ---- O += P V ----
    const u16* vp = &vbuf[cur * 4096];
#pragma unroll
    for (int ks = 0; ks < 2; ++ks)
#pragma unroll
      for (int et = 0; et < 4; ++et) {
        const int e   = et * 16 + col;
        const int byt = (ks * 64 + lhi * 16) ^ ((e & 7) << 4);
        const bf16x8 bv_ = *(const bf16x8*)(vp + e * 64 + (byt >> 1));
        oacc[0][et] = __builtin_amdgcn_mfma_f32_16x16x32_bf16(pa[0][ks], bv_, oacc[0][et], 0, 0, 0);
        oacc[1][et] = __builtin_amdgcn_mfma_f32_16x16x32_bf16(pa[1][ks], bv_, oacc[1][et], 0, 0, 0);
      }

    __syncthreads();   // drains vmcnt (next tile staged) + orders buffer reuse
    cur ^= 1;
  }

  // ---- epilogue: normalize and store fp32 ----
  float* op = out + ((size_t)b * S + qb * 128 + w * 32) * D + h * 64;
#pragma unroll
  for (int qt = 0; qt < 2; ++qt)
#pragma unroll
    for (int j = 0; j < 4; ++j) {
      const float inv = 1.0f / lrow[qt][j];
      const int row = qt * 16 + lhi * 4 + j;
#pragma unroll
      for (int et = 0; et < 4; ++et)
        op[(size_t)row * D + et * 16 + col] = oacc[qt][et][j] * inv;
    }
}

extern "C" void kernel_launch(void* const* d_in, const int* in_sizes, int n_in,
                              void* d_out, int out_size, void* d_ws, size_t ws_size,
                              hipStream_t stream)
{
  const float* x  = (const float*)d_in[0];
  const float* Wq = (const float*)d_in[1];
  const float* bq = (const float*)d_in[2];
  const float* Wk = (const float*)d_in[3];
  const float* bk = (const float*)d_in[4];
  const float* Wv = (const float*)d_in[5];
  const float* bv = (const float*)d_in[6];
  float* out = (float*)d_out;

  u16* qws  = (u16*)d_ws;                        // 16 MB
  u16* kws  = qws + (size_t)8 * 16 * 1024 * 64;  // 16 MB
  u16* vtws = kws + (size_t)8 * 16 * 1024 * 64;  // 16 MB  (total 48 MB of ws)

  dim3 blk(256);
  dim3 grid1(8, 16, 8);   // s-tile, head, batch
  hipLaunchKernelGGL(qkv_proj_kernel, grid1, blk, 0, stream,
                     x, Wq, bq, Wk, bk, Wv, bv, qws, kws, vtws);
  dim3 grid2(8, 16, 8);   // q-tile, head, batch
  hipLaunchKernelGGL(attn_kernel, grid2, blk, 0, stream,
                     qws, kws, vtws, out);
}

// Round 3
// 159.031 us; speedup vs baseline: 1.5184x; 1.5184x over previous
//
#include <hip/hip_runtime.h>
#include <hip/hip_bf16.h>

typedef unsigned short u16;
typedef __attribute__((ext_vector_type(8))) short bf16x8;
typedef __attribute__((ext_vector_type(4))) float f32x4;
typedef __attribute__((ext_vector_type(16))) float f32x16;

#define LOG2E 1.44269504088896f

__device__ __forceinline__ u16 f2bf(float f) {
  unsigned u = __float_as_uint(f);
  u += 0x7FFFu + ((u >> 16) & 1u);   // round-to-nearest-even
  return (u16)(u >> 16);
}
__device__ __forceinline__ unsigned cvtpk(float lo, float hi_) {
  unsigned r;
  asm("v_cvt_pk_bf16_f32 %0, %1, %2" : "=v"(r) : "v"(lo), "v"(hi_));
  return r;
}

// ---------------------------------------------------------------------------
// Phase 1: per-head QKV projection.
//   q_ws: [B][H][S][64] bf16, row-major, pre-scaled by 0.125*log2e
//   k_ws: [B][H][16 kv-blocks] 8KB images: byte = row*128 + ((col*2)^((row&7)<<4))
//   vt_ws: like k image but row = e (out dim) and COLUMN-PERMUTED by kappa:
//     image col (h*8+j within 16-group) holds kv = 4h + (j&3) + 8*(j>>2), so the
//     attention PV A-operand matches the MFMA C/D register order of P with NO
//     cross-lane exchange (mapping-agnostic as long as A/B layouts agree).
// ---------------------------------------------------------------------------
__global__ __launch_bounds__(256) void qkv_proj_kernel(
    const float* __restrict__ x,
    const float* __restrict__ Wq, const float* __restrict__ bq,
    const float* __restrict__ Wk, const float* __restrict__ bk,
    const float* __restrict__ Wv, const float* __restrict__ bv,
    u16* __restrict__ qws, u16* __restrict__ kws, u16* __restrict__ vtws)
{
  constexpr int S = 1024, D = 1024, H = 16;
  const int tid  = threadIdx.x;
  const int lane = tid & 63;
  const int w    = tid >> 6;
  const int st   = blockIdx.x;
  const int h    = blockIdx.y;
  const int b    = blockIdx.z;
  const int s0   = st * 128;
  const int col  = lane & 15;
  const int lhi  = lane >> 4;

  __shared__ u16 xs[128 * 72];
  __shared__ u16 wsm[3 * 64 * 72];
  __shared__ u16 ost[4 * 2304];

  {
    const int r = tid >> 4;
    const int c = (tid & 15) * 4;
#pragma unroll
    for (int p = 0; p < 8; ++p) {
      const int row = p * 16 + r;
      const float4 v = *(const float4*)(x + ((size_t)b * S + s0 + row) * D + h * 64 + c);
      ushort4 u; u.x = f2bf(v.x); u.y = f2bf(v.y); u.z = f2bf(v.z); u.w = f2bf(v.w);
      *(ushort4*)(&xs[row * 72 + c]) = u;
    }
    const float* Wp[3] = {Wq, Wk, Wv};
#pragma unroll
    for (int o = 0; o < 3; ++o) {
      const float* Wh = Wp[o] + (size_t)h * 4096;
#pragma unroll
      for (int p = 0; p < 4; ++p) {
        const int row = p * 16 + r;
        const float4 v = *(const float4*)(Wh + row * 64 + c);
        ushort4 u; u.x = f2bf(v.x); u.y = f2bf(v.y); u.z = f2bf(v.z); u.w = f2bf(v.w);
        *(ushort4*)(&wsm[o * 4608 + row * 72 + c]) = u;
      }
    }
  }
  __syncthreads();

  bf16x8 af[2][2];
#pragma unroll
  for (int qt = 0; qt < 2; ++qt)
#pragma unroll
    for (int ks = 0; ks < 2; ++ks)
      af[qt][ks] = *(const bf16x8*)(&xs[(w * 32 + qt * 16 + col) * 72 + ks * 32 + lhi * 8]);

  u16* ow = &ost[w * 2304];

#pragma unroll
  for (int o = 0; o < 3; ++o) {
    f32x4 acc[2][4];
#pragma unroll
    for (int qt = 0; qt < 2; ++qt)
#pragma unroll
      for (int et = 0; et < 4; ++et) acc[qt][et] = f32x4{0.f, 0.f, 0.f, 0.f};

#pragma unroll
    for (int et = 0; et < 4; ++et)
#pragma unroll
      for (int ks = 0; ks < 2; ++ks) {
        const bf16x8 bfr = *(const bf16x8*)(&wsm[o * 4608 + (et * 16 + col) * 72 + ks * 32 + lhi * 8]);
        acc[0][et] = __builtin_amdgcn_mfma_f32_16x16x32_bf16(af[0][ks], bfr, acc[0][et], 0, 0, 0);
        acc[1][et] = __builtin_amdgcn_mfma_f32_16x16x32_bf16(af[1][ks], bfr, acc[1][et], 0, 0, 0);
      }

    const float* bp = (o == 0) ? bq : (o == 1) ? bk : bv;
    float bias[4];
#pragma unroll
    for (int et = 0; et < 4; ++et) bias[et] = bp[h * 64 + et * 16 + col];
    const float mul = (o == 0) ? (0.125f * LOG2E) : 1.0f;  // fold 1/sqrt(HD)*log2e into Q

    if (o < 2) {
#pragma unroll
      for (int qt = 0; qt < 2; ++qt)
#pragma unroll
        for (int et = 0; et < 4; ++et)
#pragma unroll
          for (int j = 0; j < 4; ++j)
            ow[(qt * 16 + lhi * 4 + j) * 72 + et * 16 + col] =
                f2bf((acc[qt][et][j] + bias[et]) * mul);
      asm volatile("s_waitcnt lgkmcnt(0)" ::: "memory");
#pragma unroll
      for (int p = 0; p < 8; ++p) {
        const int rl = p * 4 + lhi;
        const ushort4 dta = *(const ushort4*)(&ow[rl * 72 + col * 4]);
        if (o == 0) {
          const size_t off = (((size_t)b * H + h) * S + s0 + w * 32 + rl) * 64 + col * 4;
          *(ushort4*)(qws + off) = dta;
        } else {
          const int tg  = s0 + w * 32 + rl;
          const int kb  = tg >> 6, rim = tg & 63;
          const int byt = (col * 8) ^ ((rim & 7) << 4);
          const size_t off = (((size_t)b * H + h) * 16 + kb) * 4096 + rim * 64 + (byt >> 1);
          *(ushort4*)(kws + off) = dta;
        }
      }
    } else {
      // V: stage transposed as [64 e][36 t]
#pragma unroll
      for (int qt = 0; qt < 2; ++qt)
#pragma unroll
        for (int et = 0; et < 4; ++et) {
          ushort4 u;
          u.x = f2bf(acc[qt][et][0] + bias[et]);
          u.y = f2bf(acc[qt][et][1] + bias[et]);
          u.z = f2bf(acc[qt][et][2] + bias[et]);
          u.w = f2bf(acc[qt][et][3] + bias[et]);
          *(ushort4*)(&ow[(et * 16 + col) * 36 + qt * 16 + lhi * 4]) = u;
        }
      asm volatile("s_waitcnt lgkmcnt(0)" ::: "memory");
#pragma unroll
      for (int p = 0; p < 8; ++p) {
        const int e = p * 8 + (lane >> 3);
        const int c = lane & 7;
        const ushort4 dta = *(const ushort4*)(&ow[e * 36 + c * 4]);
        const int tl  = w * 32 + c * 4;                 // 4 consecutive tokens
        const int kb  = (s0 + tl) >> 6;
        const int kc  = (s0 + tl) & 63;                 // 4-aligned
        const int m   = kc >> 2;                        // 0..15
        // kappa column remap: group m -> image col base
        const int icb = ((m >> 2) << 4) | ((m & 1) << 3) | (((m >> 1) & 1) << 2);
        const int byt = (icb * 2) ^ ((e & 7) << 4);
        const size_t off = (((size_t)b * H + h) * 16 + kb) * 4096 + e * 64 + (byt >> 1);
        *(ushort4*)(vtws + off) = dta;
      }
    }
    __syncthreads();
  }
}

// ---------------------------------------------------------------------------
// Phase 2: flash attention, swapped-operand 32x32x16 MFMA.
// Each lane owns one q-row (q = lane&31); kv split across lane<->lane^32.
// Softmax in-register; cross-half reduce via __shfl_xor(.,32) (2 ops/tile).
// P -> PV B-frag: direct cvt_pk in C/D register order; V image is
// kappa-permuted to match, so no cross-lane exchange is needed.
// ---------------------------------------------------------------------------
__global__ __launch_bounds__(256) void attn_kernel(
    const u16* __restrict__ qws, const u16* __restrict__ kws,
    const u16* __restrict__ vtws, float* __restrict__ out)
{
  constexpr int S = 1024, D = 1024, H = 16;
  const int tid  = threadIdx.x;
  const int lane = tid & 63;
  const int w    = tid >> 6;
  const int id   = blockIdx.x;
  const int qb   = id >> 7;        // 0..7
  const int bhid = id & 127;
  const int b    = bhid >> 4;
  const int h    = bhid & 15;
  const int ql   = lane & 31;
  const int hi   = lane >> 5;

  __shared__ u16 kbuf[2 * 4096];
  __shared__ u16 vbuf[2 * 4096];

  const size_t bh = (size_t)b * H + h;
  const int qrow0 = qb * 128 + w * 32;
  const u16* qbase = qws + (bh * S + qrow0) * 64;
  const u16* kimg0 = kws + bh * 16 * 4096;
  const u16* vimg0 = vtws + bh * 16 * 4096;

  // Q fragments: B-frag of mfma(K,Q): lane holds Q[ql][dc*16 + hi*8 .. +7]
  bf16x8 qf[4];
#pragma unroll
  for (int dc = 0; dc < 4; ++dc)
    qf[dc] = *(const bf16x8*)(qbase + ql * 64 + dc * 16 + hi * 8);

  f32x16 oa0, oa1;
#pragma unroll
  for (int r = 0; r < 16; ++r) { oa0[r] = 0.f; oa1[r] = 0.f; }
  float mrow = -1e30f, lrow = 0.f;

  auto stage = [&](int buf, int kb) {
    const u16* kimg = kimg0 + kb * 4096;
    const u16* vimg = vimg0 + kb * 4096;
#pragma unroll
    for (int i = 0; i < 2; ++i) {
      const int chunk = w + i * 4;   // wave-uniform
      __builtin_amdgcn_global_load_lds(
          (const __attribute__((address_space(1))) unsigned int*)(kimg + chunk * 512 + lane * 8),
          (__attribute__((address_space(3))) unsigned int*)(&kbuf[buf * 4096 + chunk * 512]),
          16, 0, 0);
      __builtin_amdgcn_global_load_lds(
          (const __attribute__((address_space(1))) unsigned int*)(vimg + chunk * 512 + lane * 8),
          (__attribute__((address_space(3))) unsigned int*)(&vbuf[buf * 4096 + chunk * 512]),
          16, 0, 0);
    }
  };

  stage(0, 0);
  __syncthreads();

  const int swz = ((ql & 7) << 4);  // XOR swizzle for this lane's image row
  int cur = 0;
  for (int kb = 0; kb < 16; ++kb) {
    if (kb < 15) stage(cur ^ 1, kb + 1);

    // ---- S^T = K Q^T : sa0 = kv[0..31], sa1 = kv[32..63] (q lane-local) ----
    const u16* kp = &kbuf[cur * 4096];
    f32x16 sa0, sa1;
#pragma unroll
    for (int r = 0; r < 16; ++r) { sa0[r] = 0.f; sa1[r] = 0.f; }
#pragma unroll
    for (int dc = 0; dc < 4; ++dc) {
      const int c = ((dc * 32 + hi * 16) ^ swz) >> 1;       // u16 units
      const bf16x8 k0 = *(const bf16x8*)(kp + ql * 64 + c);
      const bf16x8 k1 = *(const bf16x8*)(kp + (32 + ql) * 64 + c);
      sa0 = __builtin_amdgcn_mfma_f32_32x32x16_bf16(k0, qf[dc], sa0, 0, 0, 0);
      sa1 = __builtin_amdgcn_mfma_f32_32x32x16_bf16(k1, qf[dc], sa1, 0, 0, 0);
    }

    // ---- online softmax (log2 domain; per-lane row, halves via shfl_xor) ----
    float a0 = fmaxf(sa0[0], sa1[0]), a1 = fmaxf(sa0[1], sa1[1]);
    float a2 = fmaxf(sa0[2], sa1[2]), a3 = fmaxf(sa0[3], sa1[3]);
#pragma unroll
    for (int r = 4; r < 16; r += 4) {
      a0 = fmaxf(a0, fmaxf(sa0[r], sa1[r]));
      a1 = fmaxf(a1, fmaxf(sa0[r + 1], sa1[r + 1]));
      a2 = fmaxf(a2, fmaxf(sa0[r + 2], sa1[r + 2]));
      a3 = fmaxf(a3, fmaxf(sa0[r + 3], sa1[r + 3]));
    }
    float pm = fmaxf(fmaxf(a0, a1), fmaxf(a2, a3));
    pm = fmaxf(pm, __shfl_xor(pm, 32));

    // T13 defer-max: skip O-rescale while tile max stays within 2^8
    if (!__all(pm - mrow <= 8.0f)) {
      const float mnew  = fmaxf(mrow, pm);
      const float alpha = __builtin_amdgcn_exp2f(mrow - mnew);
      lrow *= alpha;
#pragma unroll
      for (int r = 0; r < 16; ++r) { oa0[r] *= alpha; oa1[r] *= alpha; }
      mrow = mnew;
    }

    float s0 = 0.f, s1 = 0.f, s2 = 0.f, s3 = 0.f;
#pragma unroll
    for (int r = 0; r < 16; r += 4) {
      sa0[r]     = __builtin_amdgcn_exp2f(sa0[r] - mrow);     s0 += sa0[r];
      sa0[r + 1] = __builtin_amdgcn_exp2f(sa0[r + 1] - mrow); s1 += sa0[r + 1];
      sa0[r + 2] = __builtin_amdgcn_exp2f(sa0[r + 2] - mrow); s2 += sa0[r + 2];
      sa0[r + 3] = __builtin_amdgcn_exp2f(sa0[r + 3] - mrow); s3 += sa0[r + 3];
      sa1[r]     = __builtin_amdgcn_exp2f(sa1[r] - mrow);     s0 += sa1[r];
      sa1[r + 1] = __builtin_amdgcn_exp2f(sa1[r + 1] - mrow); s1 += sa1[r + 1];
      sa1[r + 2] = __builtin_amdgcn_exp2f(sa1[r + 2] - mrow); s2 += sa1[r + 2];
      sa1[r + 3] = __builtin_amdgcn_exp2f(sa1[r + 3] - mrow); s3 += sa1[r + 3];
    }
    float rs = (s0 + s1) + (s2 + s3);
    rs += __shfl_xor(rs, 32);
    lrow += rs;

    // ---- P -> bf16 B-frags: direct cvt_pk in register order (kappa order) ----
    bf16x8 pf[4];
#pragma unroll
    for (int ks = 0; ks < 4; ++ks) {
      const f32x16& s_ = (ks < 2) ? sa0 : sa1;
      const int base = (ks & 1) * 8;
      union { unsigned wd[4]; bf16x8 hv; } pu;
      pu.wd[0] = cvtpk(s_[base + 0], s_[base + 1]);
      pu.wd[1] = cvtpk(s_[base + 2], s_[base + 3]);
      pu.wd[2] = cvtpk(s_[base + 4], s_[base + 5]);
      pu.wd[3] = cvtpk(s_[base + 6], s_[base + 7]);
      pf[ks] = pu.hv;
    }

    // ---- O^T += V^T P^T (V image kappa-permuted to match P order) ----
    const u16* vp = &vbuf[cur * 4096];
#pragma unroll
    for (int ks = 0; ks < 4; ++ks) {
      const int cv = ((ks * 32 + hi * 16) ^ swz) >> 1;
      const bf16x8 v0 = *(const bf16x8*)(vp + ql * 64 + cv);          // e = ql
      const bf16x8 v1 = *(const bf16x8*)(vp + (32 + ql) * 64 + cv);   // e = 32+ql
      oa0 = __builtin_amdgcn_mfma_f32_32x32x16_bf16(v0, pf[ks], oa0, 0, 0, 0);
      oa1 = __builtin_amdgcn_mfma_f32_32x32x16_bf16(v1, pf[ks], oa1, 0, 0, 0);
    }

    __syncthreads();
    cur ^= 1;
  }

  // ---- epilogue: per-lane normalize, store fp32 ----
  const float inv = 1.0f / lrow;
  float* op = out + ((size_t)b * S + qrow0 + ql) * D + h * 64;
#pragma unroll
  for (int rr = 0; rr < 4; ++rr) {
    float4 v;
    v.x = oa0[rr * 4 + 0] * inv; v.y = oa0[rr * 4 + 1] * inv;
    v.z = oa0[rr * 4 + 2] * inv; v.w = oa0[rr * 4 + 3] * inv;
    *(float4*)(op + rr * 8 + hi * 4) = v;           // e = 8*rr + 4*hi + 0..3
    float4 u;
    u.x = oa1[rr * 4 + 0] * inv; u.y = oa1[rr * 4 + 1] * inv;
    u.z = oa1[rr * 4 + 2] * inv; u.w = oa1[rr * 4 + 3] * inv;
    *(float4*)(op + 32 + rr * 8 + hi * 4) = u;      // e = 32 + 8*rr + 4*hi
  }
}

extern "C" void kernel_launch(void* const* d_in, const int* in_sizes, int n_in,
                              void* d_out, int out_size, void* d_ws, size_t ws_size,
                              hipStream_t stream)
{
  const float* x  = (const float*)d_in[0];
  const float* Wq = (const float*)d_in[1];
  const float* bq = (const float*)d_in[2];
  const float* Wk = (const float*)d_in[3];
  const float* bk = (const float*)d_in[4];
  const float* Wv = (const float*)d_in[5];
  const float* bv = (const float*)d_in[6];
  float* out = (float*)d_out;

  u16* qws  = (u16*)d_ws;
  u16* kws  = qws + (size_t)8 * 16 * 1024 * 64;
  u16* vtws = kws + (size_t)8 * 16 * 1024 * 64;

  dim3 blk(256);
  dim3 grid1(8, 16, 8);
  hipLaunchKernelGGL(qkv_proj_kernel, grid1, blk, 0, stream,
                     x, Wq, bq, Wk, bk, Wv, bv, qws, kws, vtws);
  dim3 grid2(1024);
  hipLaunchKernelGGL(attn_kernel, grid2, blk, 0, stream,
                     qws, kws, vtws, out);
}